// Round 14
// baseline (1209.658 us; speedup 1.0000x reference)
//
#include <hip/hip_runtime.h>
#include <hip/hip_bf16.h>

// LSTM B=256,T=512,I=64,H=256. 64 WGs x 256 thr (4 waves), 4-way j-split.
// Round 14: each wave computes ALL 4 gates for its 16-j block (160 weight
// VGPRs/thread, 1 wave/SIMD) -> 4x less LDS A-fragment traffic (the r13-
// discovered floor) and gates land lane-local: no gl transpose, no B1.
// One barrier/step (act double-buffered). Exchange: tagged u32 atomicExch
// publish (LLC-resident) + per-thread dwordx4 sc0 sc1 poll (round-8 proven).

#define B_TOT 256
#define T_SEQ 512
#define NIN   64
#define HID   256
#define CHUNK 16
#define JSL   64            // j per WG (4-way split)
#define ROWB  768           // LDS act row stride bytes (320 f16 = 640B data)
#define NKK   10            // K = 320 = 10*32
#define NWG   64
#define NTHR  256

typedef _Float16 half8 __attribute__((ext_vector_type(8)));
typedef float    f32x4 __attribute__((ext_vector_type(4)));
typedef unsigned u32x4 __attribute__((ext_vector_type(4)));

__device__ __forceinline__ float fast_rcp(float x){ return __builtin_amdgcn_rcpf(x); }
__device__ __forceinline__ float sigf(float v){ return fast_rcp(1.0f+__expf(-v)); }
__device__ __forceinline__ float tanhf_fast(float v){ return 1.0f-2.0f*fast_rcp(__expf(2.0f*v)+1.0f); }
__device__ __forceinline__ unsigned f2h_bits(float f){
    _Float16 h=(_Float16)f;
    return (unsigned)__builtin_bit_cast(unsigned short, h);
}

__global__ void __launch_bounds__(NTHR, 1)
lstm_scan(const float* __restrict__ x,
          const float* __restrict__ Wih,
          const float* __restrict__ Whh,
          const float* __restrict__ bih,
          const float* __restrict__ bhh,
          const float* __restrict__ Wfc,
          const float* __restrict__ bfc,
          float* __restrict__ out,
          unsigned* __restrict__ hq)    // [2][B_TOT][HID] tagged h words
{
    __shared__ __align__(16) char act[2][CHUNK*ROWB];  // dbuf, swizzled

    const int tid  = threadIdx.x;
    const int jb   = tid >> 6;       // wave 0..3 = 16-j block
    const int lane = tid & 63;
    const int lr   = lane & 15;      // A row (batch) / B col (j within block)
    const int kg   = lane >> 4;      // k-group
    const int chunk= blockIdx.x & 15;
    const int jw   = blockIdx.x >> 4;    // 0..3
    const int cb   = chunk*CHUNK;
    const int R    = tid >> 4;       // gather/x row 0..15
    const int q    = tid & 15;       // gather/x 4-col quad

    // ---- register-resident weights: ALL 4 gates for j = jw*64+jb*16+lr ----
    half8 wv[4][NKK];                // 160 VGPRs
    float bias[4];
    #pragma unroll
    for (int gg = 0; gg < 4; ++gg) {
        const int n = gg*HID + jw*JSL + jb*16 + lr;
        bias[gg] = bih[n] + bhh[n];
        #pragma unroll
        for (int kk = 0; kk < 2; ++kk)
            #pragma unroll
            for (int jj = 0; jj < 8; ++jj)
                wv[gg][kk][jj] = (_Float16)Wih[n*NIN + kk*32 + kg*8 + jj];
        #pragma unroll
        for (int kk = 2; kk < NKK; ++kk)
            #pragma unroll
            for (int jj = 0; jj < 8; ++jj)
                wv[gg][kk][jj] = (_Float16)Whh[n*HID + (kk-2)*32 + kg*8 + jj];
    }

    // ---- init act: zeros (h_0 = 0), x_0 into buf 0 ----
    for (int i = tid; i < 2*CHUNK*ROWB/4; i += NTHR) ((int*)act)[i] = 0;
    __syncthreads();
    {
        const float4 x0 = *((const float4*)(x + (size_t)(cb+R)*T_SEQ*NIN) + q);
        const unsigned lo = f2h_bits(x0.x) | (f2h_bits(x0.y) << 16);
        const unsigned hi = f2h_bits(x0.z) | (f2h_bits(x0.w) << 16);
        *(unsigned long long*)(act[0] + R*ROWB + ((q*8) ^ (R << 4))) =
            ((unsigned long long)hi << 32) | lo;
    }
    __syncthreads();

    float cst[4] = {0.f,0.f,0.f,0.f};
    float hlast[4] = {0.f,0.f,0.f,0.f};

    const int pj0 = (jw + 1) & 3, pj1v = (jw + 2) & 3, pj2v = (jw + 3) & 3;

    for (int t = 0; t < T_SEQ; ++t) {
        const char* acur = act[t & 1];
        char*       anx  = act[(t & 1) ^ 1];
        const bool  more = (t < T_SEQ-1);

        // x_{t+1} prefetch (float4, consumed before any poll asm)
        float4 xv = {0.f,0.f,0.f,0.f};
        if (more)
            xv = *((const float4*)(x + ((size_t)(cb+R)*T_SEQ + (t+1))*NIN) + q);

        // A-fragments read ONCE per wave, reused by 4 gate MFMAs
        f32x4 acc[4];
        #pragma unroll
        for (int gg = 0; gg < 4; ++gg)
            acc[gg] = (f32x4){bias[gg], bias[gg], bias[gg], bias[gg]};
        #pragma unroll
        for (int kk = 0; kk < NKK; ++kk) {
            const int off = (kk*64 + kg*16) ^ (lr << 4);
            const half8 af = *(const half8*)(acur + lr*ROWB + off);
            #pragma unroll
            for (int gg = 0; gg < 4; ++gg)
                acc[gg] = __builtin_amdgcn_mfma_f32_16x16x32_f16(
                              af, wv[gg][kk], acc[gg], 0, 0, 0);
        }

        // cell: all 4 gates lane-local (acc[gg][r]); no transpose, no barrier
        const unsigned tgt = (unsigned)(t+1);
        unsigned* hqp = hq + (size_t)(tgt & 1u)*B_TOT*HID;
        unsigned h16[4];
        #pragma unroll
        for (int r = 0; r < 4; ++r) {
            const float iv = sigf(acc[0][r]);
            const float fv = sigf(acc[1][r]);
            const float gv = tanhf_fast(acc[2][r]);
            const float ov = sigf(acc[3][r]);
            const float cc = fv*cst[r] + iv*gv;
            cst[r] = cc;
            const float hv = ov*tanhf_fast(cc);
            hlast[r] = hv;
            h16[r] = f2h_bits(hv);
        }

        // publish: 4 coalesced u32 atomicExch per wave (16-lane runs)
        if (more) {
            #pragma unroll
            for (int r = 0; r < 4; ++r)
                (void)__hip_atomic_exchange(
                    hqp + (size_t)(cb + kg*4 + r)*HID + jw*JSL + jb*16 + lr,
                    (tgt << 16) | h16[r],
                    __ATOMIC_RELAXED, __HIP_MEMORY_SCOPE_AGENT);

            // own h + x_{t+1} into act_next (LDS only)
            #pragma unroll
            for (int r = 0; r < 4; ++r) {
                const int row = kg*4 + r;
                const int c   = NIN + jw*JSL + jb*16 + lr;
                *(unsigned short*)(anx + row*ROWB + ((c*2) ^ (row << 4))) =
                    (unsigned short)h16[r];
            }
            {
                const unsigned lo = f2h_bits(xv.x) | (f2h_bits(xv.y) << 16);
                const unsigned hi = f2h_bits(xv.z) | (f2h_bits(xv.w) << 16);
                *(unsigned long long*)(anx + R*ROWB + ((q*8) ^ (R << 4))) =
                    ((unsigned long long)hi << 32) | lo;
            }

            // gather: thread polls (row R, quad q) of 3 partners
            {
                const unsigned* a0 = hqp + (size_t)(cb+R)*HID + pj0*JSL + q*4;
                const unsigned* a1 = hqp + (size_t)(cb+R)*HID + pj1v*JSL + q*4;
                const unsigned* a2 = hqp + (size_t)(cb+R)*HID + pj2v*JSL + q*4;
                u32x4 v0, v1, v2;
                for (;;) {
                    asm volatile(
                        "global_load_dwordx4 %0, %3, off sc0 sc1\n\t"
                        "global_load_dwordx4 %1, %4, off sc0 sc1\n\t"
                        "global_load_dwordx4 %2, %5, off sc0 sc1\n\t"
                        "s_waitcnt vmcnt(0)"
                        : "=&v"(v0), "=&v"(v1), "=&v"(v2)
                        : "v"(a0), "v"(a1), "v"(a2)
                        : "memory");
                    const unsigned f =
                          ((v0[0]>>16)^tgt)|((v0[1]>>16)^tgt)
                        | ((v0[2]>>16)^tgt)|((v0[3]>>16)^tgt)
                        | ((v1[0]>>16)^tgt)|((v1[1]>>16)^tgt)
                        | ((v1[2]>>16)^tgt)|((v1[3]>>16)^tgt)
                        | ((v2[0]>>16)^tgt)|((v2[1]>>16)^tgt)
                        | ((v2[2]>>16)^tgt)|((v2[3]>>16)^tgt);
                    if (f == 0u) break;
                }
                const int cA = NIN + pj0*JSL + q*4;
                const int cB = NIN + pj1v*JSL + q*4;
                const int cC = NIN + pj2v*JSL + q*4;
                const unsigned dA0 = (v0[0]&0xFFFFu)|(v0[1]<<16);
                const unsigned dA1 = (v0[2]&0xFFFFu)|(v0[3]<<16);
                const unsigned dB0 = (v1[0]&0xFFFFu)|(v1[1]<<16);
                const unsigned dB1 = (v1[2]&0xFFFFu)|(v1[3]<<16);
                const unsigned dC0 = (v2[0]&0xFFFFu)|(v2[1]<<16);
                const unsigned dC1 = (v2[2]&0xFFFFu)|(v2[3]<<16);
                *(unsigned long long*)(anx + R*ROWB + ((cA*2) ^ (R<<4))) =
                    ((unsigned long long)dA1 << 32) | dA0;
                *(unsigned long long*)(anx + R*ROWB + ((cB*2) ^ (R<<4))) =
                    ((unsigned long long)dB1 << 32) | dB0;
                *(unsigned long long*)(anx + R*ROWB + ((cC*2) ^ (R<<4))) =
                    ((unsigned long long)dC1 << 32) | dC0;
            }
            __syncthreads();   // single barrier: act_next complete
        }
    }

    // ---- final FC: lane holds h for rows kg*4+r at j = jw*64+jb*16+lr ----
    {
        const float wf = Wfc[jw*JSL + jb*16 + lr];
        #pragma unroll
        for (int r = 0; r < 4; ++r) {
            float v = wf * hlast[r];
            v += __shfl_xor(v, 1);
            v += __shfl_xor(v, 2);
            v += __shfl_xor(v, 4);
            v += __shfl_xor(v, 8);
            if (lr == 0) {
                if (jw == 0 && jb == 0) v += bfc[0];
                atomicAdd(&out[cb + kg*4 + r], v);
            }
        }
    }
}

extern "C" void kernel_launch(void* const* d_in, const int* in_sizes, int n_in,
                              void* d_out, int out_size, void* d_ws, size_t ws_size,
                              hipStream_t stream)
{
    const float* x   = (const float*)d_in[0];
    const float* Wih = (const float*)d_in[1];
    const float* Whh = (const float*)d_in[2];
    const float* bih = (const float*)d_in[3];
    const float* bhh = (const float*)d_in[4];
    const float* Wfc = (const float*)d_in[5];
    const float* bfc = (const float*)d_in[6];
    float* out = (float*)d_out;

    unsigned* hq = (unsigned*)d_ws;   // [2][256][256] tagged words

    hipMemsetAsync(hq, 0, (size_t)2*B_TOT*HID*sizeof(unsigned), stream);
    hipMemsetAsync(d_out, 0, out_size*sizeof(float), stream);
    lstm_scan<<<NWG, NTHR, 0, stream>>>(x, Wih, Whh, bih, bhh, Wfc, bfc,
                                        out, hq);
}